// Round 4
// baseline (201.570 us; speedup 1.0000x reference)
//
#include <hip/hip_runtime.h>
#include <cstdint>

using u16 = unsigned short;
typedef __bf16 bf16x8 __attribute__((ext_vector_type(8)));
typedef __bf16 bf16x4 __attribute__((ext_vector_type(4)));
typedef __bf16 bf16x2 __attribute__((ext_vector_type(2)));
typedef float f32x4 __attribute__((ext_vector_type(4)));

#define MFMA16(a, b, c) __builtin_amdgcn_mfma_f32_16x16x32_bf16((a), (b), (c), 0, 0, 0)

__device__ __forceinline__ u16 f2bf(float f) {
  union { float f; uint32_t u; } c; c.f = f;
  uint32_t u = c.u;
  u += 0x7fffu + ((u >> 16) & 1u);   // RNE
  return (u16)(u >> 16);
}

#if __has_builtin(__builtin_amdgcn_global_load_lds)
#define GLOAD_LDS16(g, l)                                                      \
  __builtin_amdgcn_global_load_lds(                                            \
      (__attribute__((address_space(1))) void*)(g),                            \
      (__attribute__((address_space(3))) void*)(l), 16, 0, 0)
#else
#define GLOAD_LDS16(g, l) do { *(uint4*)(l) = *(const uint4*)(g); } while (0)
#endif

// In-register P^T fragment build (replaces P LDS round-trip).
// Inputs: lo = s[ct_lo] (k_local = ct_lo*16 + quad*4 + r), hi = s[ct_hi=lo+1].
// Output: B-fragment bf16x8, lane(quad,l16) = P[k_local = quad*8 + j][q=l16].
// swap32 then swap16 on (X,Y): X''=[X.q0,X.q2,Y.q0,Y.q2], Y''=[X.q1,X.q3,Y.q1,Y.q3].
__device__ __forceinline__ bf16x8 ptrans(const f32x4 lo, const f32x4 hi) {
  union W { bf16x2 h; uint32_t u; } wl0, wl1, wh0, wh1;
  wl0.h[0] = (__bf16)lo[0]; wl0.h[1] = (__bf16)lo[1];
  wl1.h[0] = (__bf16)lo[2]; wl1.h[1] = (__bf16)lo[3];
  wh0.h[0] = (__bf16)hi[0]; wh0.h[1] = (__bf16)hi[1];
  wh1.h[0] = (__bf16)hi[2]; wh1.h[1] = (__bf16)hi[3];
  uint32_t a0 = wl0.u, b0 = wh0.u, a1 = wl1.u, b1 = wh1.u;
  asm("v_permlane32_swap_b32 %0, %1" : "+v"(a0), "+v"(b0));
  asm("v_permlane16_swap_b32 %0, %1" : "+v"(a0), "+v"(b0));
  asm("v_permlane32_swap_b32 %0, %1" : "+v"(a1), "+v"(b1));
  asm("v_permlane16_swap_b32 %0, %1" : "+v"(a1), "+v"(b1));
  union R { uint32_t u[4]; bf16x8 v; } r;
  r.u[0] = a0; r.u[1] = a1; r.u[2] = b0; r.u[3] = b1;
  return r.v;
}

// ---------------- fused prep: x->bf16, w_qkv^T->bf16, w_out^T->bf16 --------
__global__ __launch_bounds__(256) void prep(
    const float* __restrict__ x, const float* __restrict__ w_qkv,
    const float* __restrict__ w_out, u16* __restrict__ xb,
    u16* __restrict__ wqT, u16* __restrict__ woT) {
  const int bid = blockIdx.x, tid = threadIdx.x;
  if (bid < 4096) {
    int i = (bid * 256 + tid) * 4;
    float4 v = *(const float4*)&x[i];
    ushort4 p;
    p.x = f2bf(v.x); p.y = f2bf(v.y); p.z = f2bf(v.z); p.w = f2bf(v.w);
    *(ushort4*)&xb[i] = p;
    return;
  }
  __shared__ float tile[32][33];
  int t = bid - 4096;
  const float* in;
  u16* outp;
  int C, bx, by;
  if (t < 3072) { in = w_qkv; outp = wqT; C = 3072; bx = (t % 96) * 32; by = (t / 96) * 32; }
  else { t -= 3072; in = w_out; outp = woT; C = 1024; bx = (t % 32) * 32; by = (t / 32) * 32; }
  const int tx = tid & 31, ty = tid >> 5;
#pragma unroll
  for (int r2 = 0; r2 < 4; ++r2)
    tile[ty + r2 * 8][tx] = in[(size_t)(by + ty + r2 * 8) * C + bx + tx];
  __syncthreads();
#pragma unroll
  for (int r2 = 0; r2 < 4; ++r2)
    outp[(size_t)(bx + ty + r2 * 8) * 1024 + by + tx] = f2bf(tile[tx][ty + r2 * 8]);
}

// ---------------- GEMM 128x128 (R10, best measured): QKV scatter -----------
// grid (32,24)=768 = 256 CU x 3 resident; launch_bounds(256,3).
__global__ __launch_bounds__(256, 3) void gemm_qkv(
    const u16* __restrict__ A, const u16* __restrict__ Bt,
    const float* __restrict__ bias,
    u16* __restrict__ qb, u16* __restrict__ kb, u16* __restrict__ vb,
    int M, int N, int K) {
  __shared__ u16 As[128 * 32];
  __shared__ u16 Bs[128 * 32];
  const int tid = threadIdx.x;
  const int m0 = blockIdx.x * 128;
  const int n0 = blockIdx.y * 128;
  const int lane = tid & 63, w = tid >> 6;
  const int quad = lane >> 4, l16 = lane & 15;
  const int wr = w >> 1, wc = w & 1;

  f32x4 acc[4][4] = {};

  const int r0 = tid >> 2, p0 = tid & 3;
  const int r1 = r0 + 64;
  const int c8 = p0 ^ ((r0 >> 1) & 3);
  const u16* ga0 = A + (size_t)(m0 + r0) * K + c8 * 8;
  const u16* ga1 = A + (size_t)(m0 + r1) * K + c8 * 8;
  const u16* gb0 = Bt + (size_t)(n0 + r0) * K + c8 * 8;
  const u16* gb1 = Bt + (size_t)(n0 + r1) * K + c8 * 8;
  u16* la0 = &As[tid * 8];
  u16* la1 = &As[(tid + 256) * 8];
  u16* lb0 = &Bs[tid * 8];
  u16* lb1 = &Bs[(tid + 256) * 8];

  int aoff[4], boff[4];
#pragma unroll
  for (int i = 0; i < 4; ++i) {
    int ra = wr * 64 + i * 16 + l16;
    aoff[i] = (ra * 4 + (quad ^ ((ra >> 1) & 3))) * 8;
    int rb = wc * 64 + i * 16 + l16;
    boff[i] = (rb * 4 + (quad ^ ((rb >> 1) & 3))) * 8;
  }

  const int nIter = K >> 5;
  for (int kt = 0; kt < nIter; ++kt) {
    __syncthreads();
    const int kk = kt << 5;
    GLOAD_LDS16(ga0 + kk, la0);
    GLOAD_LDS16(ga1 + kk, la1);
    GLOAD_LDS16(gb0 + kk, lb0);
    GLOAD_LDS16(gb1 + kk, lb1);
    __syncthreads();
    bf16x8 af[4], bfr[4];
#pragma unroll
    for (int i = 0; i < 4; ++i) af[i] = *(const bf16x8*)&As[aoff[i]];
#pragma unroll
    for (int j = 0; j < 4; ++j) bfr[j] = *(const bf16x8*)&Bs[boff[j]];
#pragma unroll
    for (int i = 0; i < 4; ++i)
#pragma unroll
      for (int j = 0; j < 4; ++j)
        acc[i][j] = MFMA16(af[i], bfr[j], acc[i][j]);
  }

  const int S = 2048, NH = 16;
#pragma unroll
  for (int i = 0; i < 4; ++i) {
    const int mb = m0 + wr * 64 + i * 16 + quad * 4;
#pragma unroll
    for (int j = 0; j < 4; ++j) {
      const int n = n0 + wc * 64 + j * 16 + l16;
      const float bv = bias[n];
      const int which = n >> 10;      // 0:Q 1:K 2:V (uniform per block)
      const int hn = n & 1023;
      const int h = hn >> 6, d = hn & 63;
      const int b = mb >> 11, s = mb & 2047;
      const int bh = b * NH + h;
      if (which == 2) {
        ushort4 pk;
        pk.x = f2bf(acc[i][j][0] + bv);
        pk.y = f2bf(acc[i][j][1] + bv);
        pk.z = f2bf(acc[i][j][2] + bv);
        pk.w = f2bf(acc[i][j][3] + bv);
        *(ushort4*)&vb[((size_t)bh * 64 + d) * S + s] = pk;  // V transposed
      } else {
        // Q pre-scaled by HD^-0.5 * log2(e): scores land in exp2 domain
        const float sc = (which == 0) ? 0.18033688f : 1.0f;
        u16* dst = (which == 0) ? qb : kb;
#pragma unroll
        for (int r = 0; r < 4; ++r)
          dst[((size_t)bh * S + s + r) * 64 + d] = f2bf((acc[i][j][r] + bv) * sc);
      }
    }
  }
}

// ---------------- GEMM 64x128: out = A @ Bt^T + bias (fp32 out) ----------
__global__ __launch_bounds__(256, 2) void gemm_out(
    const u16* __restrict__ A, const u16* __restrict__ Bt,
    const float* __restrict__ bias, float* __restrict__ outf,
    int M, int N, int K) {
  __shared__ u16 As[64 * 32];
  __shared__ u16 Bs[128 * 32];
  const int tid = threadIdx.x;
  const int m0 = blockIdx.x * 64;
  const int n0 = blockIdx.y * 128;
  const int lane = tid & 63, w = tid >> 6;
  const int quad = lane >> 4, l16 = lane & 15;
  const int wr = w >> 1, wc = w & 1;

  f32x4 acc[2][4] = {};

  const int r0 = tid >> 2, p0 = tid & 3;
  const int c8 = p0 ^ ((r0 >> 1) & 3);
  const u16* ga0 = A + (size_t)(m0 + r0) * K + c8 * 8;
  const u16* gb0 = Bt + (size_t)(n0 + r0) * K + c8 * 8;
  const u16* gb1 = Bt + (size_t)(n0 + r0 + 64) * K + c8 * 8;
  u16* la0 = &As[tid * 8];
  u16* lb0 = &Bs[tid * 8];
  u16* lb1 = &Bs[(tid + 256) * 8];

  int aoff[2], boff[4];
#pragma unroll
  for (int i = 0; i < 2; ++i) {
    int ra = wr * 32 + i * 16 + l16;
    aoff[i] = (ra * 4 + (quad ^ ((ra >> 1) & 3))) * 8;
  }
#pragma unroll
  for (int j = 0; j < 4; ++j) {
    int rb = wc * 64 + j * 16 + l16;
    boff[j] = (rb * 4 + (quad ^ ((rb >> 1) & 3))) * 8;
  }

  const int nIter = K >> 5;
  for (int kt = 0; kt < nIter; ++kt) {
    __syncthreads();
    const int kk = kt << 5;
    GLOAD_LDS16(ga0 + kk, la0);
    GLOAD_LDS16(gb0 + kk, lb0);
    GLOAD_LDS16(gb1 + kk, lb1);
    __syncthreads();
    bf16x8 af[2], bfr[4];
#pragma unroll
    for (int i = 0; i < 2; ++i) af[i] = *(const bf16x8*)&As[aoff[i]];
#pragma unroll
    for (int j = 0; j < 4; ++j) bfr[j] = *(const bf16x8*)&Bs[boff[j]];
#pragma unroll
    for (int i = 0; i < 2; ++i)
#pragma unroll
      for (int j = 0; j < 4; ++j)
        acc[i][j] = MFMA16(af[i], bfr[j], acc[i][j]);
  }

#pragma unroll
  for (int i = 0; i < 2; ++i) {
    const int mb = m0 + wr * 32 + i * 16 + quad * 4;
#pragma unroll
    for (int j = 0; j < 4; ++j) {
      const int n = n0 + wc * 64 + j * 16 + l16;
      const float bv = bias[n];
#pragma unroll
      for (int r = 0; r < 4; ++r)
        outf[(size_t)(mb + r) * N + n] = acc[i][j][r] + bv;
    }
  }
}

// ---------------- flash attention v12: V from L2, K-only LDS ---------------
// v11 post-mortem: bank conflicts (2.1M) come from K/V ds_reads (128B rows
// = 32 banks, row drops out of bank fn; structural to glds-direct staging),
// and the kernel remains dependency-stall-bound at 2 waves/SIMD.
// v12: with the XCD-affine remap, each XCD's K+V (2 MB) is L2-resident ->
// V needs no LDS staging at all (common-mistake #7). Read V fragments from
// global (same granule map, no swizzle; L2-hit ~200-400cyc hides under
// QK+exp2). Removes 32 KB LDS (-> 3 blocks/CU, +50% waves/SIMD), half the
// per-tile glds (lighter barrier drains), half the bank conflicts.
__global__ __launch_bounds__(256, 3) void attn_fa(
    const u16* __restrict__ qg, const u16* __restrict__ kg,
    const u16* __restrict__ vg, u16* __restrict__ o) {
  const int S = 2048;
  // bijective XCD-affine remap: all 16 qblk of a bh on one XCD (2 MB < L2)
  const int lin = blockIdx.x;
  const int xcd = lin & 7, chunk = lin >> 3;
  const int bh = xcd * 4 + (chunk & 3);
  const int qblk = chunk >> 2;
  const int b = bh >> 4, h = bh & 15;
  const int tid = threadIdx.x, w = tid >> 6, lane = tid & 63;
  const int quad = lane >> 4, l16 = lane & 15;

  __shared__ u16 Ks[2][8192];   // [128 key-rows][8 granules], ^(row&7) swizzle

  const int q0 = qblk * 128 + w * 32;
  const u16* qp = qg + ((size_t)bh * S + q0 + l16) * 64 + quad * 8;
  const bf16x8 qf00 = *(const bf16x8*)qp;
  const bf16x8 qf01 = *(const bf16x8*)(qp + 32);
  const bf16x8 qf10 = *(const bf16x8*)(qp + 1024);
  const bf16x8 qf11 = *(const bf16x8*)(qp + 1024 + 32);

  f32x4 accO0[4] = {}, accO1[4] = {};
  f32x4 accL0 = {}, accL1 = {};    // row-sum accumulators (ones-MFMA)

  bf16x8 ones;
#pragma unroll
  for (int i = 0; i < 8; ++i) ones[i] = (__bf16)1.0f;

  const u16* kbase = kg + (size_t)bh * S * 64;
  const u16* vbase = vg + (size_t)bh * 64 * S;

  // K staging (4 insts/tile): inst seg stages rows seg*32+sr0, phys granule
  // sp0 holds logical granule sp0^(sr0&7). 8 lanes cover a full 128 B row.
  const int sr0 = tid >> 3, sp0 = tid & 7;
  const int c8s = sp0 ^ (sr0 & 7);
  const u16* kSrc = kbase + (size_t)sr0 * 64 + c8s * 8;

  // V fragment base in GLOBAL (no swizzle): row d = ct*16+l16, col =
  // kt*128 + hh*64 + quad*8 (+32 for the high granule set). Equivalent
  // values to v11's Vs reads (logical granule hh*8+quad).
  const u16* vB = vbase + (size_t)l16 * S + quad * 8;

  // K fragment granule swizzles (row&7 == l16&7 for all slabs/halves)
  const int kgA = (quad ^ (l16 & 7)) * 8;
  const int kgB = ((quad + 4) ^ (l16 & 7)) * 8;

  // preload K tile 0 into buffer 0
#pragma unroll
  for (int seg = 0; seg < 4; ++seg)
    GLOAD_LDS16(kSrc + (size_t)seg * 32 * 64, &Ks[0][(seg * 256 + tid) * 8]);

  for (int kt = 0; kt < 16; ++kt) {
    const int cur = kt & 1;
    __syncthreads();  // drains in-flight glds (issued a full 128-key tile ago)
    if (kt + 1 < 16) {
      const int nb = cur ^ 1;
#pragma unroll
      for (int seg = 0; seg < 4; ++seg)
        GLOAD_LDS16(kSrc + (size_t)((kt + 1) * 128 + seg * 32) * 64,
                    &Ks[nb][(seg * 256 + tid) * 8]);
    }
    const u16* Kc = Ks[cur];

#pragma unroll
    for (int hh = 0; hh < 2; ++hh) {
      // ---- V fragments from L2 (issued early; consumed in PV) ----
      bf16x8 vl0[4], vl1[4];
      const size_t vcol = (size_t)(kt * 128 + hh * 64);
#pragma unroll
      for (int ct = 0; ct < 4; ++ct) {
        vl0[ct] = *(const bf16x8*)&vB[(size_t)ct * 16 * S + vcol];
        vl1[ct] = *(const bf16x8*)&vB[(size_t)ct * 16 * S + vcol + 32];
      }

      // ---- S^T = K Q^T ----
      bf16x8 kf0[4], kf1[4];
#pragma unroll
      for (int ct = 0; ct < 4; ++ct) {
        const int rb = (hh * 64 + ct * 16 + l16) * 64;
        kf0[ct] = *(const bf16x8*)&Kc[rb + kgA];
        kf1[ct] = *(const bf16x8*)&Kc[rb + kgB];
      }
      f32x4 s0[4] = {}, s1[4] = {};
      __builtin_amdgcn_s_setprio(1);
#pragma unroll
      for (int ct = 0; ct < 4; ++ct) {
        s0[ct] = MFMA16(kf0[ct], qf00, s0[ct]);
        s0[ct] = MFMA16(kf1[ct], qf01, s0[ct]);
        s1[ct] = MFMA16(kf0[ct], qf10, s1[ct]);
        s1[ct] = MFMA16(kf1[ct], qf11, s1[ct]);
      }
      __builtin_amdgcn_s_setprio(0);

      // ---- P = exp2(s), raw v_exp_f32 ----
#pragma unroll
      for (int ct = 0; ct < 4; ++ct)
#pragma unroll
        for (int r = 0; r < 4; ++r) {
          s0[ct][r] = __builtin_amdgcn_exp2f(s0[ct][r]);
          s1[ct][r] = __builtin_amdgcn_exp2f(s1[ct][r]);
        }

      // ---- P^T fragments fully in-register (permlane swaps, no LDS) ----
      bf16x8 pf00 = ptrans(s0[0], s0[1]);
      bf16x8 pf01 = ptrans(s0[2], s0[3]);
      bf16x8 pf10 = ptrans(s1[0], s1[1]);
      bf16x8 pf11 = ptrans(s1[2], s1[3]);

      // ---- row sums on the matrix pipe + O^T += V^T P^T ----
      __builtin_amdgcn_s_setprio(1);
      accL0 = MFMA16(ones, pf00, accL0);
      accL0 = MFMA16(ones, pf01, accL0);
      accL1 = MFMA16(ones, pf10, accL1);
      accL1 = MFMA16(ones, pf11, accL1);

#pragma unroll
      for (int ct = 0; ct < 4; ++ct) {
        accO0[ct] = MFMA16(vl0[ct], pf00, accO0[ct]);
        accO0[ct] = MFMA16(vl1[ct], pf01, accO0[ct]);
        accO1[ct] = MFMA16(vl0[ct], pf10, accO1[ct]);
        accO1[ct] = MFMA16(vl1[ct], pf11, accO1[ct]);
      }
      __builtin_amdgcn_s_setprio(0);
    }
  }

  const float inv0 = 1.f / accL0[0], inv1 = 1.f / accL1[0];

  const int s0r = q0 + l16, s1r = q0 + 16 + l16;
#pragma unroll
  for (int ct = 0; ct < 4; ++ct) {
    ushort4 pk;
    pk.x = f2bf(accO0[ct][0] * inv0);
    pk.y = f2bf(accO0[ct][1] * inv0);
    pk.z = f2bf(accO0[ct][2] * inv0);
    pk.w = f2bf(accO0[ct][3] * inv0);
    *(ushort4*)&o[(size_t)(b * S + s0r) * 1024 + h * 64 + ct * 16 + quad * 4] = pk;
    pk.x = f2bf(accO1[ct][0] * inv1);
    pk.y = f2bf(accO1[ct][1] * inv1);
    pk.z = f2bf(accO1[ct][2] * inv1);
    pk.w = f2bf(accO1[ct][3] * inv1);
    *(ushort4*)&o[(size_t)(b * S + s1r) * 1024 + h * 64 + ct * 16 + quad * 4] = pk;
  }
}

// ---------------- launch ----------------

extern "C" void kernel_launch(void* const* d_in, const int* in_sizes, int n_in,
                              void* d_out, int out_size, void* d_ws, size_t ws_size,
                              hipStream_t stream) {
  const float* x = (const float*)d_in[0];
  const float* w_qkv = (const float*)d_in[1];
  const float* b_qkv = (const float*)d_in[2];
  const float* w_out = (const float*)d_in[3];
  const float* b_out = (const float*)d_in[4];
  float* out = (float*)d_out;

  u16* xb = (u16*)d_ws;                 // [4096,1024]
  u16* wqT = xb + 4096 * 1024;          // [3072,1024]
  u16* woT = wqT + 3072 * 1024;         // [1024,1024]
  u16* qb = woT + 1024 * 1024;          // [32,2048,64] (pre-scaled)
  u16* kb = qb + 4194304;               // [32,2048,64]
  u16* vb = kb + 4194304;               // [32,64,2048]
  u16* ao = vb + 4194304;               // [4096,1024]

  prep<<<8192, 256, 0, stream>>>(x, w_qkv, w_out, xb, wqT, woT);
  gemm_qkv<<<dim3(32, 24), 256, 0, stream>>>(xb, wqT, b_qkv, qb, kb, vb,
                                             4096, 3072, 1024);
  attn_fa<<<512, 256, 0, stream>>>(qb, kb, vb, ao);
  gemm_out<<<dim3(64, 8), 256, 0, stream>>>(ao, woT, b_out, out,
                                            4096, 1024, 1024);
}

// Round 5
// 172.747 us; speedup vs baseline: 1.1669x; 1.1669x over previous
//
#include <hip/hip_runtime.h>
#include <cstdint>

using u16 = unsigned short;
typedef __bf16 bf16x8 __attribute__((ext_vector_type(8)));
typedef __bf16 bf16x4 __attribute__((ext_vector_type(4)));
typedef __bf16 bf16x2 __attribute__((ext_vector_type(2)));
typedef float f32x4 __attribute__((ext_vector_type(4)));

#define MFMA16(a, b, c) __builtin_amdgcn_mfma_f32_16x16x32_bf16((a), (b), (c), 0, 0, 0)

__device__ __forceinline__ u16 f2bf(float f) {
  union { float f; uint32_t u; } c; c.f = f;
  uint32_t u = c.u;
  u += 0x7fffu + ((u >> 16) & 1u);   // RNE
  return (u16)(u >> 16);
}

#if __has_builtin(__builtin_amdgcn_global_load_lds)
#define GLOAD_LDS16(g, l)                                                      \
  __builtin_amdgcn_global_load_lds(                                            \
      (__attribute__((address_space(1))) void*)(g),                            \
      (__attribute__((address_space(3))) void*)(l), 16, 0, 0)
#else
#define GLOAD_LDS16(g, l) do { *(uint4*)(l) = *(const uint4*)(g); } while (0)
#endif

// In-register P^T fragment build (replaces P LDS round-trip).
// Inputs: lo = s[ct_lo] (k_local = ct_lo*16 + quad*4 + r), hi = s[ct_hi=lo+1].
// Output: B-fragment bf16x8, lane(quad,l16) = P[k_local = quad*8 + j][q=l16].
__device__ __forceinline__ bf16x8 ptrans(const f32x4 lo, const f32x4 hi) {
  union W { bf16x2 h; uint32_t u; } wl0, wl1, wh0, wh1;
  wl0.h[0] = (__bf16)lo[0]; wl0.h[1] = (__bf16)lo[1];
  wl1.h[0] = (__bf16)lo[2]; wl1.h[1] = (__bf16)lo[3];
  wh0.h[0] = (__bf16)hi[0]; wh0.h[1] = (__bf16)hi[1];
  wh1.h[0] = (__bf16)hi[2]; wh1.h[1] = (__bf16)hi[3];
  uint32_t a0 = wl0.u, b0 = wh0.u, a1 = wl1.u, b1 = wh1.u;
  asm("v_permlane32_swap_b32 %0, %1" : "+v"(a0), "+v"(b0));
  asm("v_permlane16_swap_b32 %0, %1" : "+v"(a0), "+v"(b0));
  asm("v_permlane32_swap_b32 %0, %1" : "+v"(a1), "+v"(b1));
  asm("v_permlane16_swap_b32 %0, %1" : "+v"(a1), "+v"(b1));
  union R { uint32_t u[4]; bf16x8 v; } r;
  r.u[0] = a0; r.u[1] = a1; r.u[2] = b0; r.u[3] = b1;
  return r.v;
}

// ---------------- fused prep: x->bf16, w_qkv^T->bf16, w_out^T->bf16 --------
__global__ __launch_bounds__(256) void prep(
    const float* __restrict__ x, const float* __restrict__ w_qkv,
    const float* __restrict__ w_out, u16* __restrict__ xb,
    u16* __restrict__ wqT, u16* __restrict__ woT) {
  const int bid = blockIdx.x, tid = threadIdx.x;
  if (bid < 4096) {
    int i = (bid * 256 + tid) * 4;
    float4 v = *(const float4*)&x[i];
    ushort4 p;
    p.x = f2bf(v.x); p.y = f2bf(v.y); p.z = f2bf(v.z); p.w = f2bf(v.w);
    *(ushort4*)&xb[i] = p;
    return;
  }
  __shared__ float tile[32][33];
  int t = bid - 4096;
  const float* in;
  u16* outp;
  int C, bx, by;
  if (t < 3072) { in = w_qkv; outp = wqT; C = 3072; bx = (t % 96) * 32; by = (t / 96) * 32; }
  else { t -= 3072; in = w_out; outp = woT; C = 1024; bx = (t % 32) * 32; by = (t / 32) * 32; }
  const int tx = tid & 31, ty = tid >> 5;
#pragma unroll
  for (int r2 = 0; r2 < 4; ++r2)
    tile[ty + r2 * 8][tx] = in[(size_t)(by + ty + r2 * 8) * C + bx + tx];
  __syncthreads();
#pragma unroll
  for (int r2 = 0; r2 < 4; ++r2)
    outp[(size_t)(bx + ty + r2 * 8) * 1024 + by + tx] = f2bf(tile[tx][ty + r2 * 8]);
}

// ---------------- GEMM 128x128 (R10, best measured): QKV scatter -----------
__global__ __launch_bounds__(256, 3) void gemm_qkv(
    const u16* __restrict__ A, const u16* __restrict__ Bt,
    const float* __restrict__ bias,
    u16* __restrict__ qb, u16* __restrict__ kb, u16* __restrict__ vb,
    int M, int N, int K) {
  __shared__ u16 As[128 * 32];
  __shared__ u16 Bs[128 * 32];
  const int tid = threadIdx.x;
  const int m0 = blockIdx.x * 128;
  const int n0 = blockIdx.y * 128;
  const int lane = tid & 63, w = tid >> 6;
  const int quad = lane >> 4, l16 = lane & 15;
  const int wr = w >> 1, wc = w & 1;

  f32x4 acc[4][4] = {};

  const int r0 = tid >> 2, p0 = tid & 3;
  const int r1 = r0 + 64;
  const int c8 = p0 ^ ((r0 >> 1) & 3);
  const u16* ga0 = A + (size_t)(m0 + r0) * K + c8 * 8;
  const u16* ga1 = A + (size_t)(m0 + r1) * K + c8 * 8;
  const u16* gb0 = Bt + (size_t)(n0 + r0) * K + c8 * 8;
  const u16* gb1 = Bt + (size_t)(n0 + r1) * K + c8 * 8;
  u16* la0 = &As[tid * 8];
  u16* la1 = &As[(tid + 256) * 8];
  u16* lb0 = &Bs[tid * 8];
  u16* lb1 = &Bs[(tid + 256) * 8];

  int aoff[4], boff[4];
#pragma unroll
  for (int i = 0; i < 4; ++i) {
    int ra = wr * 64 + i * 16 + l16;
    aoff[i] = (ra * 4 + (quad ^ ((ra >> 1) & 3))) * 8;
    int rb = wc * 64 + i * 16 + l16;
    boff[i] = (rb * 4 + (quad ^ ((rb >> 1) & 3))) * 8;
  }

  const int nIter = K >> 5;
  for (int kt = 0; kt < nIter; ++kt) {
    __syncthreads();
    const int kk = kt << 5;
    GLOAD_LDS16(ga0 + kk, la0);
    GLOAD_LDS16(ga1 + kk, la1);
    GLOAD_LDS16(gb0 + kk, lb0);
    GLOAD_LDS16(gb1 + kk, lb1);
    __syncthreads();
    bf16x8 af[4], bfr[4];
#pragma unroll
    for (int i = 0; i < 4; ++i) af[i] = *(const bf16x8*)&As[aoff[i]];
#pragma unroll
    for (int j = 0; j < 4; ++j) bfr[j] = *(const bf16x8*)&Bs[boff[j]];
#pragma unroll
    for (int i = 0; i < 4; ++i)
#pragma unroll
      for (int j = 0; j < 4; ++j)
        acc[i][j] = MFMA16(af[i], bfr[j], acc[i][j]);
  }

  const int S = 2048, NH = 16;
#pragma unroll
  for (int i = 0; i < 4; ++i) {
    const int mb = m0 + wr * 64 + i * 16 + quad * 4;
#pragma unroll
    for (int j = 0; j < 4; ++j) {
      const int n = n0 + wc * 64 + j * 16 + l16;
      const float bv = bias[n];
      const int which = n >> 10;      // 0:Q 1:K 2:V (uniform per block)
      const int hn = n & 1023;
      const int h = hn >> 6, d = hn & 63;
      const int b = mb >> 11, s = mb & 2047;
      const int bh = b * NH + h;
      if (which == 2) {
        ushort4 pk;
        pk.x = f2bf(acc[i][j][0] + bv);
        pk.y = f2bf(acc[i][j][1] + bv);
        pk.z = f2bf(acc[i][j][2] + bv);
        pk.w = f2bf(acc[i][j][3] + bv);
        *(ushort4*)&vb[((size_t)bh * 64 + d) * S + s] = pk;  // V transposed
      } else {
        // Q pre-scaled by HD^-0.5 * log2(e): scores land in exp2 domain
        const float sc = (which == 0) ? 0.18033688f : 1.0f;
        u16* dst = (which == 0) ? qb : kb;
#pragma unroll
        for (int r = 0; r < 4; ++r)
          dst[((size_t)bh * S + s + r) * 64 + d] = f2bf((acc[i][j][r] + bv) * sc);
      }
    }
  }
}

// ---------------- GEMM 64x128: out = A @ Bt^T + bias (fp32 out) ----------
__global__ __launch_bounds__(256, 2) void gemm_out(
    const u16* __restrict__ A, const u16* __restrict__ Bt,
    const float* __restrict__ bias, float* __restrict__ outf,
    int M, int N, int K) {
  __shared__ u16 As[64 * 32];
  __shared__ u16 Bs[128 * 32];
  const int tid = threadIdx.x;
  const int m0 = blockIdx.x * 64;
  const int n0 = blockIdx.y * 128;
  const int lane = tid & 63, w = tid >> 6;
  const int quad = lane >> 4, l16 = lane & 15;
  const int wr = w >> 1, wc = w & 1;

  f32x4 acc[2][4] = {};

  const int r0 = tid >> 2, p0 = tid & 3;
  const int c8 = p0 ^ ((r0 >> 1) & 3);
  const u16* ga0 = A + (size_t)(m0 + r0) * K + c8 * 8;
  const u16* gb0 = Bt + (size_t)(n0 + r0) * K + c8 * 8;
  const u16* gb1 = Bt + (size_t)(n0 + r0 + 64) * K + c8 * 8;
  u16* la0 = &As[tid * 8];
  u16* lb0 = &Bs[tid * 8];
  u16* lb1 = &Bs[(tid + 256) * 8];

  int aoff[2], boff[4];
#pragma unroll
  for (int i = 0; i < 2; ++i) {
    int ra = wr * 32 + i * 16 + l16;
    aoff[i] = (ra * 4 + (quad ^ ((ra >> 1) & 3))) * 8;
  }
#pragma unroll
  for (int j = 0; j < 4; ++j) {
    int rb = wc * 64 + j * 16 + l16;
    boff[j] = (rb * 4 + (quad ^ ((rb >> 1) & 3))) * 8;
  }

  const int nIter = K >> 5;
  for (int kt = 0; kt < nIter; ++kt) {
    __syncthreads();
    const int kk = kt << 5;
    GLOAD_LDS16(ga0 + kk, la0);
    GLOAD_LDS16(gb0 + kk, lb0);
    GLOAD_LDS16(gb1 + kk, lb1);
    __syncthreads();
    bf16x8 af[2], bfr[4];
#pragma unroll
    for (int i = 0; i < 2; ++i) af[i] = *(const bf16x8*)&As[aoff[i]];
#pragma unroll
    for (int j = 0; j < 4; ++j) bfr[j] = *(const bf16x8*)&Bs[boff[j]];
#pragma unroll
    for (int i = 0; i < 2; ++i)
#pragma unroll
      for (int j = 0; j < 4; ++j)
        acc[i][j] = MFMA16(af[i], bfr[j], acc[i][j]);
  }

#pragma unroll
  for (int i = 0; i < 2; ++i) {
    const int mb = m0 + wr * 32 + i * 16 + quad * 4;
#pragma unroll
    for (int j = 0; j < 4; ++j) {
      const int n = n0 + wc * 64 + j * 16 + l16;
      const float bv = bias[n];
#pragma unroll
      for (int r = 0; r < 4; ++r)
        outf[(size_t)(mb + r) * N + n] = acc[i][j][r] + bv;
    }
  }
}

// ---------------- flash attention v13: v11 + K-style V layout + ILP --------
// v12 post-mortem: conflicts 2.1M->0 with K-LDS present => ALL conflicts were
// V-path; V-from-global regressed badly (uncoalesced 4KB lane stride).
// v13 (from v11 base, best measured 47.5us):
//  a) Vs relayout to [2 hh][64 d][8 granules] -- 128B rows, exact mirror of
//     K's verified conflict-free pattern. Values read are bit-identical to
//     v12's verified global mapping (col = kt*128 + hh*64 + quad*8 (+32)).
//  b) All 32 fragment ds_reads (K+V, both hh halves) hoisted to tile top:
//     compiler can interleave QK-hh1 MFMAs with hh0 exp2/ptrans VALU and PV,
//     shortening the per-tile serial chain. VGPR ~88 -> ~220 (2 waves/SIMD
//     unchanged; LDS caps occupancy at 2 blocks/CU anyway).
__global__ __launch_bounds__(256, 2) void attn_fa(
    const u16* __restrict__ qg, const u16* __restrict__ kg,
    const u16* __restrict__ vg, u16* __restrict__ o) {
  const int S = 2048;
  // bijective XCD-affine remap: all 16 qblk of a bh on one XCD (2 MB < L2)
  const int lin = blockIdx.x;
  const int xcd = lin & 7, chunk = lin >> 3;
  const int bh = xcd * 4 + (chunk & 3);
  const int qblk = chunk >> 2;
  const int b = bh >> 4, h = bh & 15;
  const int tid = threadIdx.x, w = tid >> 6, lane = tid & 63;
  const int quad = lane >> 4, l16 = lane & 15;

  __shared__ u16 Ks[2][8192];   // [128 key-rows][8 granules], ^(row&7) swizzle
  __shared__ u16 Vs[2][8192];   // [2 hh][64 d-rows][8 granules], ^(row&7)

  const int q0 = qblk * 128 + w * 32;
  const u16* qp = qg + ((size_t)bh * S + q0 + l16) * 64 + quad * 8;
  const bf16x8 qf00 = *(const bf16x8*)qp;
  const bf16x8 qf01 = *(const bf16x8*)(qp + 32);
  const bf16x8 qf10 = *(const bf16x8*)(qp + 1024);
  const bf16x8 qf11 = *(const bf16x8*)(qp + 1024 + 32);

  f32x4 accO0[4] = {}, accO1[4] = {};
  f32x4 accL0 = {}, accL1 = {};    // row-sum accumulators (ones-MFMA)

  bf16x8 ones;
#pragma unroll
  for (int i = 0; i < 8; ++i) ones[i] = (__bf16)1.0f;

  const u16* kbase = kg + (size_t)bh * S * 64;
  const u16* vbase = vg + (size_t)bh * 64 * S;

  // K staging (4 insts/tile): inst seg stages rows seg*32+sr0, phys granule
  // sp0 holds logical granule sp0^(sr0&7). 8 lanes cover a full 128 B row.
  const int sr0 = tid >> 3, sp0 = tid & 7;
  const int c8s = sp0 ^ (sr0 & 7);
  const u16* kSrc = kbase + (size_t)sr0 * 64 + c8s * 8;
  // V staging (4 insts/tile), new layout: seg = (hh<<1)|dh stages
  // Vs[hh][dh*32 + (tid>>3)][phys g = tid&7] = V[d][kt*128 + hh*64 +
  // ((g^(d&7))*8 ...]; dest (seg*256+tid)*8 is linear per inst.
  const int vd0 = tid >> 3, vg0 = tid & 7;
  const u16* vSrc = vbase + (size_t)vd0 * S + (vg0 ^ (vd0 & 7)) * 8;

  // fragment granule swizzles (row&7 == l16&7 for all rows read); V's new
  // 128B-row layout uses the identical pair.
  const int kgA = (quad ^ (l16 & 7)) * 8;
  const int kgB = ((quad + 4) ^ (l16 & 7)) * 8;

  // preload tile 0 into buffer 0
#pragma unroll
  for (int seg = 0; seg < 4; ++seg) {
    GLOAD_LDS16(kSrc + (size_t)seg * 32 * 64, &Ks[0][(seg * 256 + tid) * 8]);
    GLOAD_LDS16(vSrc + (size_t)(seg & 1) * 32 * S + (seg >> 1) * 64,
                &Vs[0][(seg * 256 + tid) * 8]);
  }

  for (int kt = 0; kt < 16; ++kt) {
    const int cur = kt & 1;
    __syncthreads();  // drains in-flight glds (issued a full 128-key tile ago)
    const u16* Kc = Ks[cur];
    const u16* Vc = Vs[cur];

    // ---- ALL fragment reads upfront (32 x ds_read_b128) ----
    bf16x8 kf00[4], kf01[4], kf10[4], kf11[4];
    bf16x8 vf00[4], vf01[4], vf10[4], vf11[4];
#pragma unroll
    for (int ct = 0; ct < 4; ++ct) {
      const int rb0 = (ct * 16 + l16) * 64;
      const int rb1 = (64 + ct * 16 + l16) * 64;
      kf00[ct] = *(const bf16x8*)&Kc[rb0 + kgA];
      kf01[ct] = *(const bf16x8*)&Kc[rb0 + kgB];
      kf10[ct] = *(const bf16x8*)&Kc[rb1 + kgA];
      kf11[ct] = *(const bf16x8*)&Kc[rb1 + kgB];
      vf00[ct] = *(const bf16x8*)&Vc[rb0 + kgA];
      vf01[ct] = *(const bf16x8*)&Vc[rb0 + kgB];
      vf10[ct] = *(const bf16x8*)&Vc[4096 + rb0 + kgA];
      vf11[ct] = *(const bf16x8*)&Vc[4096 + rb0 + kgB];
    }

    // ---- prefetch next tile (after read issue so MFMAs start sooner) ----
    if (kt + 1 < 16) {
      const int nb = cur ^ 1;
#pragma unroll
      for (int seg = 0; seg < 4; ++seg) {
        GLOAD_LDS16(kSrc + (size_t)((kt + 1) * 128 + seg * 32) * 64,
                    &Ks[nb][(seg * 256 + tid) * 8]);
        GLOAD_LDS16(vSrc + (size_t)(seg & 1) * 32 * S + (kt + 1) * 128 +
                        (seg >> 1) * 64,
                    &Vs[nb][(seg * 256 + tid) * 8]);
      }
    }

    // ---- S^T = K Q^T, both halves ----
    f32x4 s0[4] = {}, s1[4] = {}, t0[4] = {}, t1[4] = {};
    __builtin_amdgcn_s_setprio(1);
#pragma unroll
    for (int ct = 0; ct < 4; ++ct) {
      s0[ct] = MFMA16(kf00[ct], qf00, s0[ct]);
      s0[ct] = MFMA16(kf01[ct], qf01, s0[ct]);
      s1[ct] = MFMA16(kf00[ct], qf10, s1[ct]);
      s1[ct] = MFMA16(kf01[ct], qf11, s1[ct]);
      t0[ct] = MFMA16(kf10[ct], qf00, t0[ct]);
      t0[ct] = MFMA16(kf11[ct], qf01, t0[ct]);
      t1[ct] = MFMA16(kf10[ct], qf10, t1[ct]);
      t1[ct] = MFMA16(kf11[ct], qf11, t1[ct]);
    }
    __builtin_amdgcn_s_setprio(0);

    // ---- P = exp2(s) ----
#pragma unroll
    for (int ct = 0; ct < 4; ++ct)
#pragma unroll
      for (int r = 0; r < 4; ++r) {
        s0[ct][r] = __builtin_amdgcn_exp2f(s0[ct][r]);
        s1[ct][r] = __builtin_amdgcn_exp2f(s1[ct][r]);
        t0[ct][r] = __builtin_amdgcn_exp2f(t0[ct][r]);
        t1[ct][r] = __builtin_amdgcn_exp2f(t1[ct][r]);
      }

    // ---- P^T fragments in-register ----
    bf16x8 pf00 = ptrans(s0[0], s0[1]);
    bf16x8 pf01 = ptrans(s0[2], s0[3]);
    bf16x8 pf10 = ptrans(s1[0], s1[1]);
    bf16x8 pf11 = ptrans(s1[2], s1[3]);
    bf16x8 pg00 = ptrans(t0[0], t0[1]);
    bf16x8 pg01 = ptrans(t0[2], t0[3]);
    bf16x8 pg10 = ptrans(t1[0], t1[1]);
    bf16x8 pg11 = ptrans(t1[2], t1[3]);

    // ---- row sums + O^T += V^T P^T, both halves ----
    __builtin_amdgcn_s_setprio(1);
    accL0 = MFMA16(ones, pf00, accL0);
    accL0 = MFMA16(ones, pf01, accL0);
    accL1 = MFMA16(ones, pf10, accL1);
    accL1 = MFMA16(ones, pf11, accL1);
    accL0 = MFMA16(ones, pg00, accL0);
    accL0 = MFMA16(ones, pg01, accL0);
    accL1 = MFMA16(ones, pg10, accL1);
    accL1 = MFMA16(ones, pg11, accL1);
#pragma unroll
    for (int ct = 0; ct < 4; ++ct) {
      accO0[ct] = MFMA16(vf00[ct], pf00, accO0[ct]);
      accO0[ct] = MFMA16(vf01[ct], pf01, accO0[ct]);
      accO1[ct] = MFMA16(vf00[ct], pf10, accO1[ct]);
      accO1[ct] = MFMA16(vf01[ct], pf11, accO1[ct]);
      accO0[ct] = MFMA16(vf10[ct], pg00, accO0[ct]);
      accO0[ct] = MFMA16(vf11[ct], pg01, accO0[ct]);
      accO1[ct] = MFMA16(vf10[ct], pg10, accO1[ct]);
      accO1[ct] = MFMA16(vf11[ct], pg11, accO1[ct]);
    }
    __builtin_amdgcn_s_setprio(0);
  }

  const float inv0 = 1.f / accL0[0], inv1 = 1.f / accL1[0];

  const int s0r = q0 + l16, s1r = q0 + 16 + l16;
#pragma unroll
  for (int ct = 0; ct < 4; ++ct) {
    ushort4 pk;
    pk.x = f2bf(accO0[ct][0] * inv0);
    pk.y = f2bf(accO0[ct][1] * inv0);
    pk.z = f2bf(accO0[ct][2] * inv0);
    pk.w = f2bf(accO0[ct][3] * inv0);
    *(ushort4*)&o[(size_t)(b * S + s0r) * 1024 + h * 64 + ct * 16 + quad * 4] = pk;
    pk.x = f2bf(accO1[ct][0] * inv1);
    pk.y = f2bf(accO1[ct][1] * inv1);
    pk.z = f2bf(accO1[ct][2] * inv1);
    pk.w = f2bf(accO1[ct][3] * inv1);
    *(ushort4*)&o[(size_t)(b * S + s1r) * 1024 + h * 64 + ct * 16 + quad * 4] = pk;
  }
}

// ---------------- launch ----------------

extern "C" void kernel_launch(void* const* d_in, const int* in_sizes, int n_in,
                              void* d_out, int out_size, void* d_ws, size_t ws_size,
                              hipStream_t stream) {
  const float* x = (const float*)d_in[0];
  const float* w_qkv = (const float*)d_in[1];
  const float* b_qkv = (const float*)d_in[2];
  const float* w_out = (const float*)d_in[3];
  const float* b_out = (const float*)d_in[4];
  float* out = (float*)d_out;

  u16* xb = (u16*)d_ws;                 // [4096,1024]
  u16* wqT = xb + 4096 * 1024;          // [3072,1024]
  u16* woT = wqT + 3072 * 1024;         // [1024,1024]
  u16* qb = woT + 1024 * 1024;          // [32,2048,64] (pre-scaled)
  u16* kb = qb + 4194304;               // [32,2048,64]
  u16* vb = kb + 4194304;               // [32,64,2048]
  u16* ao = vb + 4194304;               // [4096,1024]

  prep<<<8192, 256, 0, stream>>>(x, w_qkv, w_out, xb, wqT, woT);
  gemm_qkv<<<dim3(32, 24), 256, 0, stream>>>(xb, wqT, b_qkv, qb, kb, vb,
                                             4096, 3072, 1024);
  attn_fa<<<512, 256, 0, stream>>>(qb, kb, vb, ao);
  gemm_out<<<dim3(64, 8), 256, 0, stream>>>(ao, woT, b_out, out,
                                            4096, 1024, 1024);
}